// Round 19
// baseline (165.622 us; speedup 1.0000x reference)
//
#include <hip/hip_runtime.h>
#include <hip/hip_fp16.h>
#include <math.h>

typedef _Float16 half8 __attribute__((ext_vector_type(8)));
typedef float floatx4 __attribute__((ext_vector_type(4)));

__device__ __forceinline__ float leaky(float v){ return v > 0.f ? v : 0.2f*v; }

__device__ __forceinline__ float wredsum(float v){
  #pragma unroll
  for (int o=32;o>0;o>>=1) v += __shfl_xor(v,o,64);
  return v;
}

// monotone float<->uint key (order-preserving)
__device__ __forceinline__ unsigned fkey(float f){
  unsigned b = __float_as_uint(f);
  return (b & 0x80000000u) ? ~b : (b | 0x80000000u);
}
__device__ __forceinline__ float funkey(unsigned u){
  unsigned b = (u & 0x80000000u) ? (u ^ 0x80000000u) : ~u;
  return __uint_as_float(b);
}
#define KEY_NEGINF 0x007FFFFFu   // fkey(-inf)

// ---------------- prep: zeros + fp16 casts + weight transposes + folded coef vectors ----------------
__global__ void k_prep(const float* __restrict__ x, const float* __restrict__ W1,
                       const float* __restrict__ W2,
                       const float* __restrict__ al1, const float* __restrict__ ar1,
                       const float* __restrict__ al2, const float* __restrict__ ar2,
                       __half* __restrict__ xh, __half* __restrict__ w1t, __half* __restrict__ w2t,
                       float* __restrict__ qal1, float* __restrict__ qar1,
                       float* __restrict__ qal2, float* __restrict__ qar2,
                       int* __restrict__ deg, int* __restrict__ gbuf, int N, int ngbuf){
  int i = blockIdx.x*blockDim.x + threadIdx.x;
  if (i < N){ deg[i] = 0; return; }
  i -= N;
  if (i < ngbuf){ gbuf[i] = 0; return; }
  i -= ngbuf;
  const int nx = N*64;
  if (i < nx){ xh[i] = __float2half(x[i]); return; }
  i -= nx;
  if (i < 640*64){ int c = i >> 6, k = i & 63; w1t[i] = __float2half(W1[k*640 + c]); return; }
  i -= 640*64;
  if (i < 128*64){ int c = i >> 6, k = i & 63; w2t[i] = __float2half(W2[k*128 + c]); return; }
  i -= 128*64;
  if (i < 1280){
    int which = i / 640; int j = i - which*640; int k = j / 10, h = j - k*10;
    const float* av = which ? ar1 : al1;
    float s = 0.f;
    for (int c=0;c<64;c++) s += W1[k*640 + h*64 + c] * av[h*64 + c];
    (which ? qar1 : qal1)[k*10 + h] = s;
    return;
  }
  i -= 1280;
  if (i < 128){
    int which = i >> 6; int k = i & 63;
    const float* av = which ? ar2 : al2;
    float s = 0.f;
    for (int c=0;c<128;c++) s += W2[k*128 + c] * av[c];
    (which ? qar2 : qal2)[k] = s;
    return;
  }
}

// ---------------- layer1 coefs (LDS-tiled, per-block maxes) + degree histogram, range-split grid ----------------
__global__ __launch_bounds__(256) void k_coef_hist(const float* __restrict__ x,
                                                   const float* __restrict__ qal, const float* __restrict__ qar,
                                                   float* __restrict__ el, float* __restrict__ er,
                                                   unsigned* __restrict__ pmx, int N, int gxCoef,
                                                   const int* __restrict__ dst, int* __restrict__ deg, int E){
  __shared__ float xs[64][65];
  __shared__ float qs[64][20];
  __shared__ unsigned smx[20];
  const int t = threadIdx.x;
  if (blockIdx.x >= gxCoef){
    int i = (blockIdx.x - gxCoef)*256 + t;
    if (i < E) atomicAdd(&deg[dst[i]], 1);
    return;
  }
  const int base = blockIdx.x*64;
  if (t < 20) smx[t] = KEY_NEGINF;
  for (int idx = t; idx < 1280; idx += 256){
    int k = idx/20, j = idx - k*20;
    qs[k][j] = (j < 10) ? qal[k*10 + j] : qar[k*10 + (j-10)];
  }
  #pragma unroll
  for (int q=0;q<16;q++){
    int idx = t + q*256;
    int r = idx>>6, c = idx&63;
    xs[r][c] = (base + r < N) ? x[(size_t)(base+r)*64 + c] : 0.f;
  }
  __syncthreads();
  const int nl = t & 63;
  const int g  = t >> 6;
  const int n  = base + nl;
  float p[5] = {0,0,0,0,0};
  #pragma unroll 8
  for (int k=0;k<64;k++){
    float xv = xs[nl][k];
    #pragma unroll
    for (int j5=0;j5<5;j5++) p[j5] += xv * qs[k][g*5+j5];
  }
  if (n < N){
    #pragma unroll
    for (int j5=0;j5<5;j5++){
      int j = g*5 + j5;
      if (j < 10) el[(size_t)n*10 + j] = p[j5];
      else        er[(size_t)n*10 + (j-10)] = p[j5];
      atomicMax(&smx[j], fkey(p[j5]));
    }
  }
  __syncthreads();
  if (t < 20) pmx[(size_t)blockIdx.x*20 + t] = smx[t];
}

// ---------------- scan: coalesced tile-wise block scan + parallel gmx reduction ----------------
__global__ __launch_bounds__(1024) void k_scan(const int* __restrict__ deg, int* __restrict__ off,
                                               int* __restrict__ cur, int N,
                                               const unsigned* __restrict__ pmx,
                                               unsigned* __restrict__ gmx, int nblk){
  __shared__ unsigned smx[20];
  __shared__ int wsum[16];
  const int t = threadIdx.x;
  const int wid = t >> 6, lane = t & 63;
  if (t < 20) smx[t] = KEY_NEGINF;
  __syncthreads();
  if (t < 640){
    int j = t % 20, b0 = t / 20;
    unsigned m = KEY_NEGINF;
    for (int b = b0; b < nblk; b += 32) m = max(m, pmx[(size_t)b*20 + j]);
    atomicMax(&smx[j], m);
  }
  __syncthreads();
  if (t < 20) gmx[t] = smx[t];
  int carry = 0;
  const int ntile = (N + 1023) >> 10;
  for (int tile = 0; tile < ntile; ++tile){
    const int idx = (tile << 10) + t;
    const int v = (idx < N) ? deg[idx] : 0;
    int sc = v;
    #pragma unroll
    for (int o=1;o<64;o<<=1){
      int u = __shfl_up(sc, o, 64);
      if (lane >= o) sc += u;
    }
    if (lane == 63) wsum[wid] = sc;
    __syncthreads();
    if (t < 16){
      int wv = wsum[t];
      #pragma unroll
      for (int o=1;o<16;o<<=1){
        int u = __shfl_up(wv, o, 64);
        if (t >= o) wv += u;
      }
      wsum[t] = wv;
    }
    __syncthreads();
    const int waveBase = (wid > 0) ? wsum[wid-1] : 0;
    const int ex = carry + waveBase + sc - v;
    if (idx < N){ off[idx] = ex; cur[idx] = ex; }
    carry += wsum[15];
    __syncthreads();
  }
  if (t == 0) off[N] = carry;
}

// ---------------- scatter fused with final fp16 MFMA-weight computation ----------------
__global__ void k_scatw(const int* __restrict__ src, const int* __restrict__ dst,
                        int* __restrict__ cur, const float* __restrict__ el,
                        const float* __restrict__ er, const unsigned* __restrict__ gmx,
                        int* __restrict__ srcs, __half* __restrict__ aw16, int E){
  int i = blockIdx.x*blockDim.x + threadIdx.x;
  if (i >= E) return;
  int s0 = src[i], d0 = dst[i];
  int p = atomicAdd(&cur[d0], 1);
  srcs[p] = s0;
  const float* elp = el + (size_t)s0*10;
  const float* erp = er + (size_t)d0*10;
  union { _Float16 h[16]; uint4 u[2]; } w;
  #pragma unroll
  for (int h=0;h<10;h++){
    float m = leaky(funkey(gmx[h]) + funkey(gmx[10+h]));
    w.h[h] = (_Float16)__expf(leaky(elp[h] + erp[h]) - m);
  }
  #pragma unroll
  for (int h=10;h<16;h++) w.h[h] = (_Float16)0.f;
  uint4* o = reinterpret_cast<uint4*>(aw16 + (size_t)p*16);
  o[0] = w.u[0];
  o[1] = w.u[1];
}

// ---------------- layer1 aggregation: LDS-staged operands + per-node MFMA, 4 waves/block ----------------
// aw: 32 edges x 16 halfs contiguous -> 1 coalesced uint4/lane.
// B: 32 x-rows staged via 4 uint4/lane with granule-XOR swizzle (g ^= row>>3) -> 2-way-free ds_reads.
__global__ __launch_bounds__(256) void k_edge1(const __half* __restrict__ xh,
                                               const __half* __restrict__ aw16,
                                               const int* __restrict__ off,
                                               const int* __restrict__ srcs,
                                               __half* __restrict__ aggh, int N){
  __shared__ __align__(16) _Float16 bsm[4][32][64];
  __shared__ __align__(16) _Float16 asm_[4][32][16];
  const int wid = threadIdx.x >> 6;
  const int l   = threadIdx.x & 63;
  const int n = blockIdx.x*4 + wid;
  if (n >= N) return;
  const int lr = l & 15, lk = l >> 4;
  const int beg = off[n], end = off[n+1];
  _Float16 (*bw)[64] = bsm[wid];
  _Float16 (*aswp)[16] = asm_[wid];
  float s = 0.f;
  floatx4 acc0 = {0.f,0.f,0.f,0.f}, acc1 = {0.f,0.f,0.f,0.f};
  floatx4 acc2 = {0.f,0.f,0.f,0.f}, acc3 = {0.f,0.f,0.f,0.f};
  for (int c0 = beg; c0 < end; c0 += 32){
    const int sv = (c0 + l < end) ? srcs[c0 + l] : 0;
    // stage aw (1 uint4/lane, fully coalesced; OOB edges -> 0)
    {
      int e = l >> 1, part = l & 1;
      int p = c0 + e;
      uint4 v = make_uint4(0,0,0,0);
      if (p < end) v = *reinterpret_cast<const uint4*>(aw16 + (size_t)p*16 + part*8);
      *reinterpret_cast<uint4*>(&aswp[e][part*8]) = v;
    }
    // stage B rows (4 uint4/lane; 8 lanes per 128B row; swizzled granules)
    #pragma unroll
    for (int q=0;q<4;q++){
      int linear = q*64 + l;
      int row = linear >> 3;
      int c8  = linear & 7;
      int rn  = __shfl(sv, row, 64);
      uint4 v = *reinterpret_cast<const uint4*>(xh + (size_t)rn*64 + c8*8);
      int gw = c8 ^ (row >> 3);
      *reinterpret_cast<uint4*>(&bw[row][gw*8]) = v;
    }
    asm volatile("s_waitcnt lgkmcnt(0)" ::: "memory");   // same-wave LDS write->read
    half8 aw, b0, b1, b2, b3;
    #pragma unroll
    for (int j=0;j<8;j++){
      const int row = lk*8 + j;
      const int sw  = lk;            // row>>3
      const int hi  = lr >> 3;       // 0/1
      const int e0  = lr & 7;
      aw[j] = aswp[row][lr];
      s += (float)aw[j];
      b0[j] = bw[row][((hi    ) ^ sw)*8 + e0];
      b1[j] = bw[row][((2 + hi) ^ sw)*8 + e0];
      b2[j] = bw[row][((4 + hi) ^ sw)*8 + e0];
      b3[j] = bw[row][((6 + hi) ^ sw)*8 + e0];
    }
    acc0 = __builtin_amdgcn_mfma_f32_16x16x32_f16(aw, b0, acc0, 0, 0, 0);
    acc1 = __builtin_amdgcn_mfma_f32_16x16x32_f16(aw, b1, acc1, 0, 0, 0);
    acc2 = __builtin_amdgcn_mfma_f32_16x16x32_f16(aw, b2, acc2, 0, 0, 0);
    acc3 = __builtin_amdgcn_mfma_f32_16x16x32_f16(aw, b3, acc3, 0, 0, 0);
  }
  s += __shfl_xor(s,16,64);
  s += __shfl_xor(s,32,64);
  const float rs = (lr < 10 && s > 0.f) ? 1.f/s : 0.f;
  #pragma unroll
  for (int j=0;j<4;j++){
    int h = lk*4 + j;
    float rj = __shfl(rs, h, 64);
    if (h < 10){
      __half* op = aggh + (size_t)n*640 + h*64;
      op[lr]      = __float2half(acc0[j] * rj);
      op[16 + lr] = __float2half(acc1[j] * rj);
      op[32 + lr] = __float2half(acc2[j] * rj);
      op[48 + lr] = __float2half(acc3[j] * rj);
    }
  }
}

// ---------------- layer1 post-GEMM + fused layer2 coefs ----------------
__global__ __launch_bounds__(256) void k_ep1(const __half* __restrict__ aggh,
                                             const __half* __restrict__ w1t,
                                             const float* __restrict__ bias1,
                                             __half* __restrict__ h1h,
                                             const float* __restrict__ qal2,
                                             const float* __restrict__ qar2,
                                             float* __restrict__ el2, float* __restrict__ er2, int M){
  const int w = threadIdx.x >> 6, l = threadIdx.x & 63;
  const int m0 = blockIdx.x*64 + w*16;
  const int lr = l & 15, lk = l >> 4;
  int arow = m0 + lr; if (arow >= M) arow = M-1;
  float hsum[4][4];
  #pragma unroll
  for (int t=0;t<4;t++)
    #pragma unroll
    for (int j=0;j<4;j++) hsum[t][j] = 0.f;
  for (int h=0;h<10;h++){
    const __half* ap = aggh + (size_t)arow*640 + h*64;
    half8 a0 = *reinterpret_cast<const half8*>(ap + lk*8);
    half8 a1 = *reinterpret_cast<const half8*>(ap + 32 + lk*8);
    #pragma unroll
    for (int t=0;t<4;t++){
      const __half* bp = w1t + (size_t)(h*64 + t*16 + lr)*64 + lk*8;
      half8 b0 = *reinterpret_cast<const half8*>(bp);
      half8 b1 = *reinterpret_cast<const half8*>(bp + 32);
      floatx4 z = {0.f,0.f,0.f,0.f};
      z = __builtin_amdgcn_mfma_f32_16x16x32_f16(a0, b0, z, 0, 0, 0);
      z = __builtin_amdgcn_mfma_f32_16x16x32_f16(a1, b1, z, 0, 0, 0);
      float bb = bias1[h*64 + t*16 + lr];
      #pragma unroll
      for (int j=0;j<4;j++) hsum[t][j] += fmaxf(z[j] + bb, 0.f);
    }
  }
  #pragma unroll
  for (int t=0;t<4;t++)
    #pragma unroll
    for (int j=0;j<4;j++){
      int r = m0 + lk*4 + j;
      if (r < M) h1h[(size_t)r*64 + t*16 + lr] = __float2half(hsum[t][j]);
    }
  float pl[4] = {0,0,0,0}, pr[4] = {0,0,0,0};
  #pragma unroll
  for (int t=0;t<4;t++){
    float qa = qal2[t*16 + lr];
    float qr = qar2[t*16 + lr];
    #pragma unroll
    for (int j=0;j<4;j++){ pl[j] += hsum[t][j]*qa; pr[j] += hsum[t][j]*qr; }
  }
  #pragma unroll
  for (int o=1;o<16;o<<=1)
    #pragma unroll
    for (int j=0;j<4;j++){ pl[j] += __shfl_xor(pl[j],o,64); pr[j] += __shfl_xor(pr[j],o,64); }
  if (lr == 0){
    #pragma unroll
    for (int j=0;j<4;j++){
      int r = m0 + lk*4 + j;
      if (r < M){ el2[r] = pl[j]; er2[r] = pr[j]; }
    }
  }
}

// ---------------- layer2 aggregation (el2 L2-resident; no max pass), 4 nodes/block ----------------
__global__ __launch_bounds__(256) void k_edge2(const __half* __restrict__ h1h,
                                               const float* __restrict__ el2,
                                               const float* __restrict__ er,
                                               const int* __restrict__ off,
                                               const int* __restrict__ srcs,
                                               __half* __restrict__ agg2h, int N){
  const int lane = threadIdx.x & 63;
  const int n = blockIdx.x*4 + (threadIdx.x >> 6);
  if (n >= N) return;
  const int beg = off[n], end = off[n+1];
  const float ern = er[n];
  float s = 0.f, acc = 0.f;
  for (int c0 = beg; c0 < end; c0 += 64){
    const bool vl = (c0 + lane < end);
    const int sv = vl ? srcs[c0 + lane] : 0;
    const float gv = vl ? el2[sv] : -INFINITY;
    const float wv = __expf(leaky(gv + ern));
    s += wv;
    const int cn = min(64, end - c0);
    for (int j = 0; j < cn; j += 8){
      const int nv = min(8, cn - j);
      float hv[8], wj[8];
      #pragma unroll
      for (int jj=0;jj<8;jj++){
        if (jj < nv){
          int sj = __shfl(sv, j+jj, 64);
          hv[jj] = __half2float(h1h[(size_t)sj*64 + lane]);
          wj[jj] = __shfl(wv, j+jj, 64);
        }
      }
      #pragma unroll
      for (int jj=0;jj<8;jj++) if (jj < nv) acc += wj[jj]*hv[jj];
    }
  }
  s = wredsum(s);
  const float rs = (s > 0.f) ? 1.f/s : 0.f;
  agg2h[(size_t)n*64 + lane] = __float2half(acc * rs);
}

// ---------------- layer2 post-GEMM fused with pre-reduced per-graph max ----------------
__global__ __launch_bounds__(256) void k_l2g(const __half* __restrict__ ah,
                                             const __half* __restrict__ wt,
                                             const float* __restrict__ bias2,
                                             const int* __restrict__ gid,
                                             int* __restrict__ gbuf, int M){
  __shared__ float hs[64][65];
  const int w = threadIdx.x >> 6, l = threadIdx.x & 63;
  const int base = blockIdx.x*64;
  const int m0 = base + w*16;
  const int c0 = blockIdx.y*64;
  const int lr = l & 15, lk = l >> 4;
  int arow = m0 + lr; if (arow >= M) arow = M-1;
  half8 a0 = *reinterpret_cast<const half8*>(ah + (size_t)arow*64 + lk*8);
  half8 a1 = *reinterpret_cast<const half8*>(ah + (size_t)arow*64 + 32 + lk*8);
  #pragma unroll
  for (int t=0;t<4;t++){
    const __half* bp = wt + (size_t)(c0 + t*16 + lr)*64 + lk*8;
    half8 b0 = *reinterpret_cast<const half8*>(bp);
    half8 b1 = *reinterpret_cast<const half8*>(bp + 32);
    floatx4 z = {0.f,0.f,0.f,0.f};
    z = __builtin_amdgcn_mfma_f32_16x16x32_f16(a0, b0, z, 0, 0, 0);
    z = __builtin_amdgcn_mfma_f32_16x16x32_f16(a1, b1, z, 0, 0, 0);
    float bb = bias2[c0 + t*16 + lr];
    #pragma unroll
    for (int j=0;j<4;j++)
      hs[w*16 + lk*4 + j][t*16 + lr] = fmaxf(z[j] + bb, 0.f);
  }
  __syncthreads();
  const int col = threadIdx.x & 63;
  const int rg  = threadIdx.x >> 6;
  int curg = -1; float mx = 0.f;
  for (int r = rg*16; r < rg*16 + 16; ++r){
    int gr = base + r;
    if (gr >= M) break;
    int gg = gid[gr];
    if (gg != curg){
      if (curg >= 0) atomicMax(&gbuf[curg*128 + c0 + col], __float_as_int(mx));
      curg = gg; mx = 0.f;
    }
    mx = fmaxf(mx, hs[r][col]);
  }
  if (curg >= 0) atomicMax(&gbuf[curg*128 + c0 + col], __float_as_int(mx));
}

// ---------------- per-graph 2-layer MLP ----------------
__global__ __launch_bounds__(128) void k_mlp(const int* __restrict__ g,
                                             const float* __restrict__ lw1, const float* __restrict__ lb1,
                                             const float* __restrict__ lw2, const float* __restrict__ lb2,
                                             float* __restrict__ out){
  int b = blockIdx.x, t = threadIdx.x;
  __shared__ float gs[128];
  __shared__ float ys[128];
  gs[t] = __int_as_float(g[b*128 + t]);
  __syncthreads();
  float y = lb1[t];
  for (int k=0;k<128;k++) y += gs[k]*lw1[k*128 + t];
  y = fmaxf(y, 0.f);
  ys[t] = y * lw2[t];
  __syncthreads();
  for (int o=64;o>0;o>>=1){
    if (t < o) ys[t] += ys[t+o];
    __syncthreads();
  }
  if (t == 0) out[b] = fmaxf(ys[0] + lb2[0], 0.f);
}

extern "C" void kernel_launch(void* const* d_in, const int* in_sizes, int n_in,
                              void* d_out, int out_size, void* d_ws, size_t ws_size,
                              hipStream_t stream){
  const float* x   = (const float*)d_in[0];
  const int*   src = (const int*)d_in[1];
  const int*   dst = (const int*)d_in[2];
  const int*   gid = (const int*)d_in[3];
  const float* W1  = (const float*)d_in[4];
  const float* al1 = (const float*)d_in[5];
  const float* ar1 = (const float*)d_in[6];
  const float* b1  = (const float*)d_in[7];
  const float* W2  = (const float*)d_in[8];
  const float* al2 = (const float*)d_in[9];
  const float* ar2 = (const float*)d_in[10];
  const float* b2  = (const float*)d_in[11];
  const float* lw1 = (const float*)d_in[12];
  const float* lb1 = (const float*)d_in[13];
  const float* lw2 = (const float*)d_in[14];
  const float* lb2 = (const float*)d_in[15];
  float* out = (float*)d_out;

  const int N = in_sizes[0] / 64;
  const int E = in_sizes[1];
  const int G = out_size;

  char* w = (char*)d_ws;
  size_t p = 0;
  auto alloc = [&](size_t bytes)->char*{ char* r = w + p; p += (bytes + 255) & ~size_t(255); return r; };
  int*      deg   = (int*)alloc((size_t)N*4);
  int*      off   = (int*)alloc((size_t)(N+1)*4);
  int*      cur   = (int*)alloc((size_t)N*4);
  int*      srcs  = (int*)alloc((size_t)E*4);
  float*    el1   = (float*)alloc((size_t)N*10*4);
  float*    er1   = (float*)alloc((size_t)N*10*4);
  unsigned* gmx   = (unsigned*)alloc(20*4);
  __half*   aw16  = (__half*)alloc((size_t)E*16*2);
  __half*   xh    = (__half*)alloc((size_t)N*64*2);
  __half*   w1t   = (__half*)alloc((size_t)640*64*2);
  __half*   w2t   = (__half*)alloc((size_t)128*64*2);
  float*    qal1  = (float*)alloc((size_t)640*4);
  float*    qar1  = (float*)alloc((size_t)640*4);
  float*    qal2  = (float*)alloc((size_t)64*4);
  float*    qar2  = (float*)alloc((size_t)64*4);
  __half*   aggh  = (__half*)alloc((size_t)N*640*2);
  __half*   h1h   = (__half*)alloc((size_t)N*64*2);
  __half*   agg2h = (__half*)alloc((size_t)N*64*2);
  int*      gbuf  = (int*)alloc((size_t)G*128*4);
  const int gx  = (N + 63) / 64;
  unsigned* pmx   = (unsigned*)alloc((size_t)gx*20*4);
  float*    el2 = el1;
  float*    er2 = er1;

  const int prep_total = N + G*128 + N*64 + 640*64 + 128*64 + 1280 + 128;
  const int histBlocks = (E + 255) / 256;

  k_prep     <<<dim3((prep_total+255)/256), dim3(256), 0, stream>>>(x, W1, W2, al1, ar1, al2, ar2,
                                                                    xh, w1t, w2t, qal1, qar1, qal2, qar2,
                                                                    deg, gbuf, N, G*128);
  k_coef_hist<<<dim3(gx + histBlocks), dim3(256), 0, stream>>>(x, qal1, qar1, el1, er1, pmx, N, gx,
                                                               dst, deg, E);
  k_scan     <<<dim3(1), dim3(1024), 0, stream>>>(deg, off, cur, N, pmx, gmx, gx);
  k_scatw    <<<dim3(histBlocks), dim3(256), 0, stream>>>(src, dst, cur, el1, er1, gmx, srcs, aw16, E);

  // layer 1
  k_edge1    <<<dim3((N+3)/4), dim3(256), 0, stream>>>(xh, aw16, off, srcs, aggh, N);
  k_ep1      <<<dim3(gx), dim3(256), 0, stream>>>(aggh, w1t, b1, h1h, qal2, qar2, el2, er2, N);

  // layer 2
  k_edge2    <<<dim3((N+3)/4), dim3(256), 0, stream>>>(h1h, el2, er2, off, srcs, agg2h, N);
  k_l2g      <<<dim3(gx, 2), dim3(256), 0, stream>>>(agg2h, w2t, b2, gid, gbuf, N);

  // readout
  k_mlp      <<<dim3(G), dim3(128), 0, stream>>>(gbuf, lw1, lb1, lw2, lb2, out);
}

// Round 20
// 163.400 us; speedup vs baseline: 1.0136x; 1.0136x over previous
//
#include <hip/hip_runtime.h>
#include <hip/hip_fp16.h>
#include <math.h>

typedef _Float16 half8 __attribute__((ext_vector_type(8)));
typedef float floatx4 __attribute__((ext_vector_type(4)));

__device__ __forceinline__ float leaky(float v){ return v > 0.f ? v : 0.2f*v; }

__device__ __forceinline__ float wredsum(float v){
  #pragma unroll
  for (int o=32;o>0;o>>=1) v += __shfl_xor(v,o,64);
  return v;
}

// monotone float<->uint key (order-preserving)
__device__ __forceinline__ unsigned fkey(float f){
  unsigned b = __float_as_uint(f);
  return (b & 0x80000000u) ? ~b : (b | 0x80000000u);
}
__device__ __forceinline__ float funkey(unsigned u){
  unsigned b = (u & 0x80000000u) ? (u ^ 0x80000000u) : ~u;
  return __uint_as_float(b);
}
#define KEY_NEGINF 0x007FFFFFu   // fkey(-inf)

// ---------------- prep: zeros + fp16 casts + weight transposes + folded coef vectors ----------------
__global__ void k_prep(const float* __restrict__ x, const float* __restrict__ W1,
                       const float* __restrict__ W2,
                       const float* __restrict__ al1, const float* __restrict__ ar1,
                       const float* __restrict__ al2, const float* __restrict__ ar2,
                       __half* __restrict__ xh, __half* __restrict__ w1t, __half* __restrict__ w2t,
                       float* __restrict__ qal1, float* __restrict__ qar1,
                       float* __restrict__ qal2, float* __restrict__ qar2,
                       int* __restrict__ deg, int* __restrict__ gbuf, int N, int ngbuf){
  int i = blockIdx.x*blockDim.x + threadIdx.x;
  if (i < N){ deg[i] = 0; return; }
  i -= N;
  if (i < ngbuf){ gbuf[i] = 0; return; }
  i -= ngbuf;
  const int nx = N*64;
  if (i < nx){ xh[i] = __float2half(x[i]); return; }
  i -= nx;
  if (i < 640*64){ int c = i >> 6, k = i & 63; w1t[i] = __float2half(W1[k*640 + c]); return; }
  i -= 640*64;
  if (i < 128*64){ int c = i >> 6, k = i & 63; w2t[i] = __float2half(W2[k*128 + c]); return; }
  i -= 128*64;
  if (i < 1280){
    int which = i / 640; int j = i - which*640; int k = j / 10, h = j - k*10;
    const float* av = which ? ar1 : al1;
    float s = 0.f;
    for (int c=0;c<64;c++) s += W1[k*640 + h*64 + c] * av[h*64 + c];
    (which ? qar1 : qal1)[k*10 + h] = s;
    return;
  }
  i -= 1280;
  if (i < 128){
    int which = i >> 6; int k = i & 63;
    const float* av = which ? ar2 : al2;
    float s = 0.f;
    for (int c=0;c<128;c++) s += W2[k*128 + c] * av[c];
    (which ? qar2 : qal2)[k] = s;
    return;
  }
}

// ---------------- layer1 coefs (LDS-tiled, per-block maxes) + degree histogram, range-split grid ----------------
__global__ __launch_bounds__(256) void k_coef_hist(const float* __restrict__ x,
                                                   const float* __restrict__ qal, const float* __restrict__ qar,
                                                   float* __restrict__ el, float* __restrict__ er,
                                                   unsigned* __restrict__ pmx, int N, int gxCoef,
                                                   const int* __restrict__ dst, int* __restrict__ deg, int E){
  __shared__ float xs[64][65];
  __shared__ float qs[64][20];
  __shared__ unsigned smx[20];
  const int t = threadIdx.x;
  if (blockIdx.x >= gxCoef){
    int i = (blockIdx.x - gxCoef)*256 + t;
    if (i < E) atomicAdd(&deg[dst[i]], 1);
    return;
  }
  const int base = blockIdx.x*64;
  if (t < 20) smx[t] = KEY_NEGINF;
  for (int idx = t; idx < 1280; idx += 256){
    int k = idx/20, j = idx - k*20;
    qs[k][j] = (j < 10) ? qal[k*10 + j] : qar[k*10 + (j-10)];
  }
  #pragma unroll
  for (int q=0;q<16;q++){
    int idx = t + q*256;
    int r = idx>>6, c = idx&63;
    xs[r][c] = (base + r < N) ? x[(size_t)(base+r)*64 + c] : 0.f;
  }
  __syncthreads();
  const int nl = t & 63;
  const int g  = t >> 6;
  const int n  = base + nl;
  float p[5] = {0,0,0,0,0};
  #pragma unroll 8
  for (int k=0;k<64;k++){
    float xv = xs[nl][k];
    #pragma unroll
    for (int j5=0;j5<5;j5++) p[j5] += xv * qs[k][g*5+j5];
  }
  if (n < N){
    #pragma unroll
    for (int j5=0;j5<5;j5++){
      int j = g*5 + j5;
      if (j < 10) el[(size_t)n*10 + j] = p[j5];
      else        er[(size_t)n*10 + (j-10)] = p[j5];
      atomicMax(&smx[j], fkey(p[j5]));
    }
  }
  __syncthreads();
  if (t < 20) pmx[(size_t)blockIdx.x*20 + t] = smx[t];
}

// ---------------- scan: coalesced tile-wise block scan + parallel gmx reduction ----------------
__global__ __launch_bounds__(1024) void k_scan(const int* __restrict__ deg, int* __restrict__ off,
                                               int* __restrict__ cur, int N,
                                               const unsigned* __restrict__ pmx,
                                               unsigned* __restrict__ gmx, int nblk){
  __shared__ unsigned smx[20];
  __shared__ int wsum[16];
  const int t = threadIdx.x;
  const int wid = t >> 6, lane = t & 63;
  if (t < 20) smx[t] = KEY_NEGINF;
  __syncthreads();
  if (t < 640){
    int j = t % 20, b0 = t / 20;
    unsigned m = KEY_NEGINF;
    for (int b = b0; b < nblk; b += 32) m = max(m, pmx[(size_t)b*20 + j]);
    atomicMax(&smx[j], m);
  }
  __syncthreads();
  if (t < 20) gmx[t] = smx[t];
  int carry = 0;
  const int ntile = (N + 1023) >> 10;
  for (int tile = 0; tile < ntile; ++tile){
    const int idx = (tile << 10) + t;
    const int v = (idx < N) ? deg[idx] : 0;
    int sc = v;
    #pragma unroll
    for (int o=1;o<64;o<<=1){
      int u = __shfl_up(sc, o, 64);
      if (lane >= o) sc += u;
    }
    if (lane == 63) wsum[wid] = sc;
    __syncthreads();
    if (t < 16){
      int wv = wsum[t];
      #pragma unroll
      for (int o=1;o<16;o<<=1){
        int u = __shfl_up(wv, o, 64);
        if (t >= o) wv += u;
      }
      wsum[t] = wv;
    }
    __syncthreads();
    const int waveBase = (wid > 0) ? wsum[wid-1] : 0;
    const int ex = carry + waveBase + sc - v;
    if (idx < N){ off[idx] = ex; cur[idx] = ex; }
    carry += wsum[15];
    __syncthreads();
  }
  if (t == 0) off[N] = carry;
}

// ---------------- scatter fused with final fp16 MFMA-weight computation ----------------
__global__ void k_scatw(const int* __restrict__ src, const int* __restrict__ dst,
                        int* __restrict__ cur, const float* __restrict__ el,
                        const float* __restrict__ er, const unsigned* __restrict__ gmx,
                        int* __restrict__ srcs, __half* __restrict__ aw16, int E){
  int i = blockIdx.x*blockDim.x + threadIdx.x;
  if (i >= E) return;
  int s0 = src[i], d0 = dst[i];
  int p = atomicAdd(&cur[d0], 1);
  srcs[p] = s0;
  const float* elp = el + (size_t)s0*10;
  const float* erp = er + (size_t)d0*10;
  union { _Float16 h[16]; uint4 u[2]; } w;
  #pragma unroll
  for (int h=0;h<10;h++){
    float m = leaky(funkey(gmx[h]) + funkey(gmx[10+h]));
    w.h[h] = (_Float16)__expf(leaky(elp[h] + erp[h]) - m);
  }
  #pragma unroll
  for (int h=10;h<16;h++) w.h[h] = (_Float16)0.f;
  uint4* o = reinterpret_cast<uint4*>(aw16 + (size_t)p*16);
  o[0] = w.u[0];
  o[1] = w.u[1];
}

// ---------------- layer1 aggregation: pure {stream aw16, gather xh, MFMA} (r18 best) ----------------
__global__ __launch_bounds__(64) void k_edge1(const __half* __restrict__ xh,
                                              const __half* __restrict__ aw16,
                                              const int* __restrict__ off,
                                              const int* __restrict__ srcs,
                                              __half* __restrict__ aggh, int N){
  const int l = threadIdx.x;
  const int n = blockIdx.x;
  const int lr = l & 15, lk = l >> 4;
  const int beg = off[n], end = off[n+1];
  float s = 0.f;
  floatx4 acc0 = {0.f,0.f,0.f,0.f}, acc1 = {0.f,0.f,0.f,0.f};
  floatx4 acc2 = {0.f,0.f,0.f,0.f}, acc3 = {0.f,0.f,0.f,0.f};
  for (int c0 = beg; c0 < end; c0 += 32){
    int sv = (c0 + l < end) ? srcs[c0 + l] : 0;
    int sj[8];
    #pragma unroll
    for (int j=0;j<8;j++) sj[j] = __shfl(sv, lk*8 + j, 64);
    half8 aw;
    #pragma unroll
    for (int j=0;j<8;j++){
      int p = c0 + lk*8 + j;
      _Float16 wv = (_Float16)0.f;
      if (p < end) wv = *(const _Float16*)(aw16 + (size_t)p*16 + lr);
      aw[j] = wv;
      s += (float)wv;
    }
    half8 b0, b1, b2, b3;
    #pragma unroll
    for (int j=0;j<8;j++){
      const __half* rp = xh + (size_t)sj[j]*64;
      b0[j] = *(const _Float16*)(rp + lr);
      b1[j] = *(const _Float16*)(rp + 16 + lr);
      b2[j] = *(const _Float16*)(rp + 32 + lr);
      b3[j] = *(const _Float16*)(rp + 48 + lr);
    }
    acc0 = __builtin_amdgcn_mfma_f32_16x16x32_f16(aw, b0, acc0, 0, 0, 0);
    acc1 = __builtin_amdgcn_mfma_f32_16x16x32_f16(aw, b1, acc1, 0, 0, 0);
    acc2 = __builtin_amdgcn_mfma_f32_16x16x32_f16(aw, b2, acc2, 0, 0, 0);
    acc3 = __builtin_amdgcn_mfma_f32_16x16x32_f16(aw, b3, acc3, 0, 0, 0);
  }
  s += __shfl_xor(s,16,64);
  s += __shfl_xor(s,32,64);
  const float rs = (lr < 10 && s > 0.f) ? 1.f/s : 0.f;
  #pragma unroll
  for (int j=0;j<4;j++){
    int h = lk*4 + j;
    float rj = __shfl(rs, h, 64);
    if (h < 10){
      __half* op = aggh + (size_t)n*640 + h*64;
      op[lr]      = __float2half(acc0[j] * rj);
      op[16 + lr] = __float2half(acc1[j] * rj);
      op[32 + lr] = __float2half(acc2[j] * rj);
      op[48 + lr] = __float2half(acc3[j] * rj);
    }
  }
}

// ---------------- layer1 post-GEMM + fused layer2 coefs ----------------
__global__ __launch_bounds__(256) void k_ep1(const __half* __restrict__ aggh,
                                             const __half* __restrict__ w1t,
                                             const float* __restrict__ bias1,
                                             __half* __restrict__ h1h,
                                             const float* __restrict__ qal2,
                                             const float* __restrict__ qar2,
                                             float* __restrict__ el2, float* __restrict__ er2, int M){
  const int w = threadIdx.x >> 6, l = threadIdx.x & 63;
  const int m0 = blockIdx.x*64 + w*16;
  const int lr = l & 15, lk = l >> 4;
  int arow = m0 + lr; if (arow >= M) arow = M-1;
  float hsum[4][4];
  #pragma unroll
  for (int t=0;t<4;t++)
    #pragma unroll
    for (int j=0;j<4;j++) hsum[t][j] = 0.f;
  for (int h=0;h<10;h++){
    const __half* ap = aggh + (size_t)arow*640 + h*64;
    half8 a0 = *reinterpret_cast<const half8*>(ap + lk*8);
    half8 a1 = *reinterpret_cast<const half8*>(ap + 32 + lk*8);
    #pragma unroll
    for (int t=0;t<4;t++){
      const __half* bp = w1t + (size_t)(h*64 + t*16 + lr)*64 + lk*8;
      half8 b0 = *reinterpret_cast<const half8*>(bp);
      half8 b1 = *reinterpret_cast<const half8*>(bp + 32);
      floatx4 z = {0.f,0.f,0.f,0.f};
      z = __builtin_amdgcn_mfma_f32_16x16x32_f16(a0, b0, z, 0, 0, 0);
      z = __builtin_amdgcn_mfma_f32_16x16x32_f16(a1, b1, z, 0, 0, 0);
      float bb = bias1[h*64 + t*16 + lr];
      #pragma unroll
      for (int j=0;j<4;j++) hsum[t][j] += fmaxf(z[j] + bb, 0.f);
    }
  }
  #pragma unroll
  for (int t=0;t<4;t++)
    #pragma unroll
    for (int j=0;j<4;j++){
      int r = m0 + lk*4 + j;
      if (r < M) h1h[(size_t)r*64 + t*16 + lr] = __float2half(hsum[t][j]);
    }
  float pl[4] = {0,0,0,0}, pr[4] = {0,0,0,0};
  #pragma unroll
  for (int t=0;t<4;t++){
    float qa = qal2[t*16 + lr];
    float qr = qar2[t*16 + lr];
    #pragma unroll
    for (int j=0;j<4;j++){ pl[j] += hsum[t][j]*qa; pr[j] += hsum[t][j]*qr; }
  }
  #pragma unroll
  for (int o=1;o<16;o<<=1)
    #pragma unroll
    for (int j=0;j<4;j++){ pl[j] += __shfl_xor(pl[j],o,64); pr[j] += __shfl_xor(pr[j],o,64); }
  if (lr == 0){
    #pragma unroll
    for (int j=0;j<4;j++){
      int r = m0 + lk*4 + j;
      if (r < M){ el2[r] = pl[j]; er2[r] = pr[j]; }
    }
  }
}

// ---------------- layer2 aggregation (el2 L2-resident; no max pass), 4 nodes/block ----------------
__global__ __launch_bounds__(256) void k_edge2(const __half* __restrict__ h1h,
                                               const float* __restrict__ el2,
                                               const float* __restrict__ er,
                                               const int* __restrict__ off,
                                               const int* __restrict__ srcs,
                                               __half* __restrict__ agg2h, int N){
  const int lane = threadIdx.x & 63;
  const int n = blockIdx.x*4 + (threadIdx.x >> 6);
  if (n >= N) return;
  const int beg = off[n], end = off[n+1];
  const float ern = er[n];
  float s = 0.f, acc = 0.f;
  for (int c0 = beg; c0 < end; c0 += 64){
    const bool vl = (c0 + lane < end);
    const int sv = vl ? srcs[c0 + lane] : 0;
    const float gv = vl ? el2[sv] : -INFINITY;
    const float wv = __expf(leaky(gv + ern));
    s += wv;
    const int cn = min(64, end - c0);
    for (int j = 0; j < cn; j += 8){
      const int nv = min(8, cn - j);
      float hv[8], wj[8];
      #pragma unroll
      for (int jj=0;jj<8;jj++){
        if (jj < nv){
          int sj = __shfl(sv, j+jj, 64);
          hv[jj] = __half2float(h1h[(size_t)sj*64 + lane]);
          wj[jj] = __shfl(wv, j+jj, 64);
        }
      }
      #pragma unroll
      for (int jj=0;jj<8;jj++) if (jj < nv) acc += wj[jj]*hv[jj];
    }
  }
  s = wredsum(s);
  const float rs = (s > 0.f) ? 1.f/s : 0.f;
  agg2h[(size_t)n*64 + lane] = __float2half(acc * rs);
}

// ---------------- layer2 post-GEMM fused with pre-reduced per-graph max ----------------
__global__ __launch_bounds__(256) void k_l2g(const __half* __restrict__ ah,
                                             const __half* __restrict__ wt,
                                             const float* __restrict__ bias2,
                                             const int* __restrict__ gid,
                                             int* __restrict__ gbuf, int M){
  __shared__ float hs[64][65];
  const int w = threadIdx.x >> 6, l = threadIdx.x & 63;
  const int base = blockIdx.x*64;
  const int m0 = base + w*16;
  const int c0 = blockIdx.y*64;
  const int lr = l & 15, lk = l >> 4;
  int arow = m0 + lr; if (arow >= M) arow = M-1;
  half8 a0 = *reinterpret_cast<const half8*>(ah + (size_t)arow*64 + lk*8);
  half8 a1 = *reinterpret_cast<const half8*>(ah + (size_t)arow*64 + 32 + lk*8);
  #pragma unroll
  for (int t=0;t<4;t++){
    const __half* bp = wt + (size_t)(c0 + t*16 + lr)*64 + lk*8;
    half8 b0 = *reinterpret_cast<const half8*>(bp);
    half8 b1 = *reinterpret_cast<const half8*>(bp + 32);
    floatx4 z = {0.f,0.f,0.f,0.f};
    z = __builtin_amdgcn_mfma_f32_16x16x32_f16(a0, b0, z, 0, 0, 0);
    z = __builtin_amdgcn_mfma_f32_16x16x32_f16(a1, b1, z, 0, 0, 0);
    float bb = bias2[c0 + t*16 + lr];
    #pragma unroll
    for (int j=0;j<4;j++)
      hs[w*16 + lk*4 + j][t*16 + lr] = fmaxf(z[j] + bb, 0.f);
  }
  __syncthreads();
  const int col = threadIdx.x & 63;
  const int rg  = threadIdx.x >> 6;
  int curg = -1; float mx = 0.f;
  for (int r = rg*16; r < rg*16 + 16; ++r){
    int gr = base + r;
    if (gr >= M) break;
    int gg = gid[gr];
    if (gg != curg){
      if (curg >= 0) atomicMax(&gbuf[curg*128 + c0 + col], __float_as_int(mx));
      curg = gg; mx = 0.f;
    }
    mx = fmaxf(mx, hs[r][col]);
  }
  if (curg >= 0) atomicMax(&gbuf[curg*128 + c0 + col], __float_as_int(mx));
}

// ---------------- per-graph 2-layer MLP ----------------
__global__ __launch_bounds__(128) void k_mlp(const int* __restrict__ g,
                                             const float* __restrict__ lw1, const float* __restrict__ lb1,
                                             const float* __restrict__ lw2, const float* __restrict__ lb2,
                                             float* __restrict__ out){
  int b = blockIdx.x, t = threadIdx.x;
  __shared__ float gs[128];
  __shared__ float ys[128];
  gs[t] = __int_as_float(g[b*128 + t]);
  __syncthreads();
  float y = lb1[t];
  for (int k=0;k<128;k++) y += gs[k]*lw1[k*128 + t];
  y = fmaxf(y, 0.f);
  ys[t] = y * lw2[t];
  __syncthreads();
  for (int o=64;o>0;o>>=1){
    if (t < o) ys[t] += ys[t+o];
    __syncthreads();
  }
  if (t == 0) out[b] = fmaxf(ys[0] + lb2[0], 0.f);
}

extern "C" void kernel_launch(void* const* d_in, const int* in_sizes, int n_in,
                              void* d_out, int out_size, void* d_ws, size_t ws_size,
                              hipStream_t stream){
  const float* x   = (const float*)d_in[0];
  const int*   src = (const int*)d_in[1];
  const int*   dst = (const int*)d_in[2];
  const int*   gid = (const int*)d_in[3];
  const float* W1  = (const float*)d_in[4];
  const float* al1 = (const float*)d_in[5];
  const float* ar1 = (const float*)d_in[6];
  const float* b1  = (const float*)d_in[7];
  const float* W2  = (const float*)d_in[8];
  const float* al2 = (const float*)d_in[9];
  const float* ar2 = (const float*)d_in[10];
  const float* b2  = (const float*)d_in[11];
  const float* lw1 = (const float*)d_in[12];
  const float* lb1 = (const float*)d_in[13];
  const float* lw2 = (const float*)d_in[14];
  const float* lb2 = (const float*)d_in[15];
  float* out = (float*)d_out;

  const int N = in_sizes[0] / 64;
  const int E = in_sizes[1];
  const int G = out_size;

  char* w = (char*)d_ws;
  size_t p = 0;
  auto alloc = [&](size_t bytes)->char*{ char* r = w + p; p += (bytes + 255) & ~size_t(255); return r; };
  int*      deg   = (int*)alloc((size_t)N*4);
  int*      off   = (int*)alloc((size_t)(N+1)*4);
  int*      cur   = (int*)alloc((size_t)N*4);
  int*      srcs  = (int*)alloc((size_t)E*4);
  float*    el1   = (float*)alloc((size_t)N*10*4);
  float*    er1   = (float*)alloc((size_t)N*10*4);
  unsigned* gmx   = (unsigned*)alloc(20*4);
  __half*   aw16  = (__half*)alloc((size_t)E*16*2);
  __half*   xh    = (__half*)alloc((size_t)N*64*2);
  __half*   w1t   = (__half*)alloc((size_t)640*64*2);
  __half*   w2t   = (__half*)alloc((size_t)128*64*2);
  float*    qal1  = (float*)alloc((size_t)640*4);
  float*    qar1  = (float*)alloc((size_t)640*4);
  float*    qal2  = (float*)alloc((size_t)64*4);
  float*    qar2  = (float*)alloc((size_t)64*4);
  __half*   aggh  = (__half*)alloc((size_t)N*640*2);
  __half*   h1h   = (__half*)alloc((size_t)N*64*2);
  __half*   agg2h = (__half*)alloc((size_t)N*64*2);
  int*      gbuf  = (int*)alloc((size_t)G*128*4);
  const int gx  = (N + 63) / 64;
  unsigned* pmx   = (unsigned*)alloc((size_t)gx*20*4);
  float*    el2 = el1;
  float*    er2 = er1;

  const int prep_total = N + G*128 + N*64 + 640*64 + 128*64 + 1280 + 128;
  const int histBlocks = (E + 255) / 256;

  k_prep     <<<dim3((prep_total+255)/256), dim3(256), 0, stream>>>(x, W1, W2, al1, ar1, al2, ar2,
                                                                    xh, w1t, w2t, qal1, qar1, qal2, qar2,
                                                                    deg, gbuf, N, G*128);
  k_coef_hist<<<dim3(gx + histBlocks), dim3(256), 0, stream>>>(x, qal1, qar1, el1, er1, pmx, N, gx,
                                                               dst, deg, E);
  k_scan     <<<dim3(1), dim3(1024), 0, stream>>>(deg, off, cur, N, pmx, gmx, gx);
  k_scatw    <<<dim3(histBlocks), dim3(256), 0, stream>>>(src, dst, cur, el1, er1, gmx, srcs, aw16, E);

  // layer 1
  k_edge1    <<<dim3(N), dim3(64), 0, stream>>>(xh, aw16, off, srcs, aggh, N);
  k_ep1      <<<dim3(gx), dim3(256), 0, stream>>>(aggh, w1t, b1, h1h, qal2, qar2, el2, er2, N);

  // layer 2
  k_edge2    <<<dim3((N+3)/4), dim3(256), 0, stream>>>(h1h, el2, er2, off, srcs, agg2h, N);
  k_l2g      <<<dim3(gx, 2), dim3(256), 0, stream>>>(agg2h, w2t, b2, gid, gbuf, N);

  // readout
  k_mlp      <<<dim3(G), dim3(128), 0, stream>>>(gbuf, lw1, lb1, lw2, lb2, out);
}